// Round 5
// baseline (16809.248 us; speedup 1.0000x reference)
//
#include <hip/hip_runtime.h>

#define NTOT   2048
#define BATCH  32
#define TSTEPS 500
#define NBLK   256
#define COLS   8                 // columns per block (256*8 = 2048)
#define CAP    304               // CSR capacity/col (nnz ~ Binom(2048,0.1): max ~266)
#define RELEMS (BATCH * NTOT)    // 65536
#define OUT_BASE (TSTEPS * RELEMS)
#define NGRP   8
#define GRPSZ  (NBLK / NGRP)     // 32

static __device__ __forceinline__ float act(float u) {
  const float x = 3.0f * u - 2.0f;      // sigmoid(3u-2), precise expf
  return 1.0f / (1.0f + expf(-x));
}

__global__ void alif_init(unsigned int* bar) { bar[threadIdx.x] = 0u; }  // 256 words

__global__ __launch_bounds__(256, 1) void alif_main(
    const float* __restrict__ u0,
    const float* __restrict__ ext,
    const float* __restrict__ wrec,
    const float* __restrict__ mask,
    const float* __restrict__ sign,
    const float* __restrict__ dtv,
    float* __restrict__ rbuf,            // [2][NTOT][BATCH] f32 (transposed r)
    float* __restrict__ usave,           // d_out (f32!)
    unsigned int* __restrict__ bar) {    // striped: grp g at [16g], global at [128]
  const int tid  = threadIdx.x;
  const int lane = tid & 63;
  const int wv   = tid >> 6;
  const int c0   = blockIdx.x * COLS;

  __shared__ uint2 csr[COLS * CAP];      // (.x = f32 weight bits, .y = k*BATCH elem offset)
  __shared__ int   nnz[COLS];
  __shared__ int   maxn_s;

  // ---- build CSR once: wave wv owns local cols {2wv, 2wv+1} (same cols it dots) ----
  for (int cl = 2 * wv; cl < 2 * wv + 2; ++cl) {
    const int c = c0 + cl;
    int base = 0;
    for (int k0 = 0; k0 < NTOT; k0 += 64) {
      const int k = k0 + lane;
      const float mv = mask[c * NTOT + k];
      const bool nz = (mv != 0.0f);
      const unsigned long long bal = __ballot(nz);
      if (nz) {
        const int pos = base + __popcll(bal & ((1ull << lane) - 1ull));
        // mask(=1.0)*relu(wrec)*sign : every factor exact in f32
        const float w = mv * fmaxf(wrec[c * NTOT + k], 0.0f) * sign[k];
        if (pos < CAP) csr[cl * CAP + pos] = make_uint2(__float_as_uint(w), (unsigned)(k * BATCH));
      }
      base += __popcll(bal);
    }
    if (lane == 0) nnz[cl] = (base < CAP) ? base : CAP;
  }
  __syncthreads();
  if (tid == 0) {
    int m = 0;
    for (int i = 0; i < COLS; ++i) m = (nnz[i] > m) ? nnz[i] : m;
    maxn_s = (m + 7) & ~7;
  }
  __syncthreads();
  const int maxn = maxn_s;
  for (int cl = 2 * wv; cl < 2 * wv + 2; ++cl)        // zero-pad: fmaf(r,0,acc) exact no-op
    for (int i = nnz[cl] + lane; i < maxn; i += 64)
      csr[cl * CAP + i] = make_uint2(0u, 0u);

  // ---- per-thread state: (batch b_e, column c_e); 32-thread group per column ----
  const int cl_e = tid >> 5;             // 0..7
  const int b_e  = tid & 31;
  const int c_e  = c0 + cl_e;
  const float dtc = dtv[c_e];
  const float omd = 1.0f - dtc;
  float u = u0[b_e * NTOT + c_e];
  rbuf[c_e * BATCH + b_e] = act(u);      // r_0 -> phase 0 (f32)

  const uint2* __restrict__ ce = csr + cl_e * CAP;
  const int g = blockIdx.x & (NGRP - 1);

  for (int t = 0; t < TSTEPS; ++t) {
    // ---- grid barrier: publish r[t] (two-level, monotonic targets) ----
    __syncthreads();                      // all block stores issued
    if (tid == 0) {
      __threadfence();                    // release: wb L2 so stores reach LLC
      const unsigned prev =
          __hip_atomic_fetch_add(&bar[16 * g], 1u, __ATOMIC_ACQ_REL, __HIP_MEMORY_SCOPE_AGENT);
      if (((prev + 1u) & (GRPSZ - 1u)) == 0u)          // group complete for this step
        __hip_atomic_fetch_add(&bar[128], 1u, __ATOMIC_ACQ_REL, __HIP_MEMORY_SCOPE_AGENT);
      const unsigned gt = (unsigned)(t + 1) * NGRP;
      while (__hip_atomic_load(&bar[128], __ATOMIC_RELAXED, __HIP_MEMORY_SCOPE_AGENT) < gt)
        __builtin_amdgcn_s_sleep(1);
      __threadfence();                    // acquire: inv L1 (this CU) + L2 (this XCD)
    }
    __syncthreads();

    // ext issued right after barrier; consumed only in epilogue
    const float e = ext[t * RELEMS + b_e * NTOT + c_e];

    // ---- exact-f32 sparse dot: drive_rec[b_e][c_e] ----
    const float* __restrict__ rrow = rbuf + (t & 1) * RELEMS + b_e;
    float a0 = 0.f, a1 = 0.f, a2 = 0.f, a3 = 0.f;
    for (int i = 0; i < maxn; i += 4) {
      const uint2 e0 = ce[i], e1 = ce[i + 1], e2 = ce[i + 2], e3 = ce[i + 3];
      const float r0 = rrow[e0.y], r1 = rrow[e1.y], r2 = rrow[e2.y], r3 = rrow[e3.y];
      a0 = fmaf(r0, __uint_as_float(e0.x), a0);
      a1 = fmaf(r1, __uint_as_float(e1.x), a1);
      a2 = fmaf(r2, __uint_as_float(e2.x), a2);
      a3 = fmaf(r3, __uint_as_float(e3.x), a3);
    }
    const float rec = (a0 + a1) + (a2 + a3);

    // ---- update: drive = rec + MUE + ext; leaky integrate (all f32) ----
    const float drv = (rec + 0.5f) + e;
    u = u * omd + drv * dtc;
    usave[t * RELEMS + b_e * NTOT + c_e] = u;                     // f32 store!
    rbuf[((t + 1) & 1) * RELEMS + c_e * BATCH + b_e] = act(u);    // f32 r for next step
  }
}

// ---- outsave[t][b][o] = act(u_t) @ wout, u_t = (t==0 ? u0 : usave[t-1]) ----
__global__ __launch_bounds__(256) void alif_readout(
    const float* __restrict__ u0,
    const float* __restrict__ usave,
    const float* __restrict__ wout,
    float* __restrict__ outs) {
  const int wg = blockIdx.x * 4 + (threadIdx.x >> 6);   // 0..15999 = (t,b)
  const int lane = threadIdx.x & 63;
  const int t = wg >> 5, b = wg & 31;
  float a0 = 0.f, a1 = 0.f;
  for (int k0 = 0; k0 < NTOT; k0 += 64) {
    const int k = k0 + lane;
    const float uv = (t == 0) ? u0[b * NTOT + k] : usave[(t - 1) * RELEMS + b * NTOT + k];
    const float r = act(uv);
    const float2 w2 = *(const float2*)(wout + k * 2);
    a0 = fmaf(r, w2.x, a0);
    a1 = fmaf(r, w2.y, a1);
  }
#pragma unroll
  for (int off = 32; off; off >>= 1) {
    a0 += __shfl_xor(a0, off, 64);
    a1 += __shfl_xor(a1, off, 64);
  }
  if (lane == 0) {
    outs[t * (BATCH * 2) + b * 2 + 0] = a0;
    outs[t * (BATCH * 2) + b * 2 + 1] = a1;
  }
}

extern "C" void kernel_launch(void* const* d_in, const int* in_sizes, int n_in,
                              void* d_out, int out_size, void* d_ws, size_t ws_size,
                              hipStream_t stream) {
  const float* u0   = (const float*)d_in[0];
  const float* ext  = (const float*)d_in[1];
  const float* wrec = (const float*)d_in[2];
  const float* mask = (const float*)d_in[3];
  const float* sign = (const float*)d_in[4];
  const float* wout = (const float*)d_in[5];
  const float* dtv  = (const float*)d_in[6];
  float* out = (float*)d_out;

  char* w = (char*)d_ws;
  unsigned int* bar  = (unsigned int*)w;                 // 1 KB (256 words, striped)
  float*        rbuf = (float*)(w + 1024);               // 2*65536*4 = 512 KB

  alif_init<<<dim3(1), dim3(256), 0, stream>>>(bar);

  void* args[] = {(void*)&u0, (void*)&ext, (void*)&wrec, (void*)&mask, (void*)&sign,
                  (void*)&dtv, (void*)&rbuf, (void*)&out, (void*)&bar};
  hipLaunchCooperativeKernel((const void*)alif_main, dim3(NBLK), dim3(256),
                             args, 0, stream);

  alif_readout<<<dim3(TSTEPS * BATCH / 4), dim3(256), 0, stream>>>(
      u0, out, wout, out + OUT_BASE);
}